// Round 7
// baseline (131.692 us; speedup 1.0000x reference)
//
#include <hip/hip_runtime.h>
#include <hip/hip_bf16.h>

// bs=2, seq=2048, d_model=512, heads=8, d_k=64, WINDOW=2
#define SEQ 2048
#define DM  512
#define BS  2
#define NH  8
#define DK  64
#define MROWS (BS * SEQ)   // 4096
#define GK 64              // GEMM K-tile (two 16x16x32 MFMA k-steps per barrier pair)

typedef __attribute__((ext_vector_type(8))) short bf16x8;
typedef __attribute__((ext_vector_type(4))) float f32x4;

__device__ __forceinline__ unsigned short f2bf(float f) {
    unsigned int u = __float_as_uint(f);
    u += 0x7fff + ((u >> 16) & 1);
    return (unsigned short)(u >> 16);
}
__device__ __forceinline__ float bf2f(unsigned short b) {
    return __uint_as_float((unsigned int)b << 16);
}

// async global->LDS, 16B per lane. LDS dest must be wave-uniform base + lane*16.
#define GLDS16(g, l) __builtin_amdgcn_global_load_lds( \
    (const __attribute__((address_space(1))) void*)(g), \
    (__attribute__((address_space(3))) void*)(unsigned int)(unsigned long long)(l), 16, 0, 0)

// ---------------- prep (small): transpose+cvt weights; init vsum = SEQ*bv ----------------
__global__ __launch_bounds__(256) void prep_w(const float* __restrict__ Wq, const float* __restrict__ Wk,
                                              const float* __restrict__ Wv, const float* __restrict__ Wo,
                                              const float* __restrict__ bv_,
                                              unsigned short* __restrict__ WqT, unsigned short* __restrict__ WkT,
                                              unsigned short* __restrict__ WvT, unsigned short* __restrict__ WoT,
                                              float* __restrict__ vsum)
{
    __shared__ float tile[32][33];
    const int bid = blockIdx.x;            // 0..1023
    if (bid == 0) {
        #pragma unroll
        for (int t = 0; t < 4; ++t) {
            const int idx = threadIdx.x * 4 + t;           // 0..1023
            vsum[idx] = (float)SEQ * bv_[idx & (DM - 1)];
        }
    }
    const int z = bid >> 8;
    const int tl = bid & 255;
    const float* W = (z == 0) ? Wq : (z == 1) ? Wk : (z == 2) ? Wv : Wo;
    unsigned short* T = (z == 0) ? WqT : (z == 1) ? WkT : (z == 2) ? WvT : WoT;
    const int n0 = (tl & 15) * 32, k0 = (tl >> 4) * 32;
    const int tx = threadIdx.x & 31;
    const int ty = threadIdx.x >> 5;
    #pragma unroll
    for (int r = 0; r < 32; r += 8)
        tile[ty + r][tx] = W[(size_t)(k0 + ty + r) * DM + n0 + tx];
    __syncthreads();
    #pragma unroll
    for (int r = 0; r < 32; r += 8)
        T[(size_t)(n0 + ty + r) * DM + k0 + tx] = f2bf(tile[tx][ty + r]);
}

// ---------------- QKV projection GEMM with fused f32->bf16 A-staging ----------------
// C(bf16, 4096x512) = cvt_bf16(A f32) @ BT(bf16)^T + bias.  Tile 128x64, GK=64.
// Grid (8,32,3) = 768 blocks (3/CU balanced). A f32 strips re-read 8x but L3-resident.
// A staged via registers (load f32 -> RNE cvt -> ds_write); B via global_load_lds.
// z==2 (V) also accumulates raw per-column sums into vsum (bias pre-folded).
__global__ __launch_bounds__(256) void gemm_qkv_cvt(const float* __restrict__ q,
                                                    const float* __restrict__ k,
                                                    const float* __restrict__ v,
                                                    const unsigned short* __restrict__ WqT,
                                                    const unsigned short* __restrict__ WkT,
                                                    const unsigned short* __restrict__ WvT,
                                                    const float* __restrict__ bq, const float* __restrict__ bk,
                                                    const float* __restrict__ bvp,
                                                    unsigned short* __restrict__ Qb, unsigned short* __restrict__ Kb,
                                                    unsigned short* __restrict__ Vb, float* __restrict__ vsum)
{
    // A: [0,8192) shorts as [kk][row128][32]; B at 8192: [kk][row64][32]  (24 KB)
    __shared__ unsigned short S[12288];

    const float* Af; const unsigned short* BT; const float* bias; unsigned short* C; float* vs;
    if (blockIdx.z == 0)      { Af = q; BT = WqT; bias = bq; C = Qb; vs = nullptr; }
    else if (blockIdx.z == 1) { Af = k; BT = WkT; bias = bk; C = Kb; vs = nullptr; }
    else                      { Af = v; BT = WvT; bias = bvp; C = Vb; vs = vsum; }

    const int tid  = threadIdx.x;
    const int lane = tid & 63;
    const int wave = tid >> 6;
    const int wm = (wave & 1) * 64;       // wave tile 64x32
    const int wn = (wave >> 1) * 32;
    const int m0 = blockIdx.y * 128;
    const int n0 = blockIdx.x * 64;
    const int l15 = lane & 15;
    const int q8  = (lane >> 4) * 8;

    f32x4 acc[4][2];
    #pragma unroll
    for (int i = 0; i < 4; ++i)
        #pragma unroll
        for (int j = 0; j < 2; ++j)
            acc[i][j] = (f32x4){0.f, 0.f, 0.f, 0.f};

    // A-staging mapping: pass p covers rows p*16 + (tid>>4), cols (tid&15)*4 .. +3
    const int arow = tid >> 4;             // 0..15
    const int akl  = (tid & 15) * 4;       // 0..60
    const int awoff = ((akl >> 5) * 4096) + (akl & 31);   // + row*32 (shorts)

    // B chunks: 512 x 16B per K-tile, 2 per thread.  LDS B region [kk][n][32].
    const unsigned short* gb[2];
    unsigned short* lb[2];
    #pragma unroll
    for (int it = 0; it < 2; ++it) {
        const int c = tid + it * 256;
        const int n  = (c >> 2) & 63;
        const int kk = c >> 8;
        gb[it] = BT + (size_t)(n0 + n) * DM + kk * 32 + (c & 3) * 8;
        lb[it] = &S[8192 + c * 8];
    }

    for (int k0 = 0; k0 < DM; k0 += GK) {
        #pragma unroll
        for (int it = 0; it < 2; ++it)
            GLDS16(gb[it] + k0, lb[it]);

        float4 av[8];
        #pragma unroll
        for (int p = 0; p < 8; ++p)
            av[p] = *(const float4*)(Af + (size_t)(m0 + p * 16 + arow) * DM + k0 + akl);
        #pragma unroll
        for (int p = 0; p < 8; ++p) {
            ushort4 o;
            o.x = f2bf(av[p].x); o.y = f2bf(av[p].y); o.z = f2bf(av[p].z); o.w = f2bf(av[p].w);
            *(ushort4*)&S[awoff + (p * 16 + arow) * 32] = o;
        }
        __syncthreads();

        #pragma unroll
        for (int kk = 0; kk < 2; ++kk) {
            bf16x8 af[4], bfr[2];
            #pragma unroll
            for (int i = 0; i < 4; ++i)
                af[i] = *(const bf16x8*)&S[kk * 4096 + (wm + i * 16 + l15) * 32 + q8];
            #pragma unroll
            for (int j = 0; j < 2; ++j)
                bfr[j] = *(const bf16x8*)&S[8192 + kk * 2048 + (wn + j * 16 + l15) * 32 + q8];
            #pragma unroll
            for (int i = 0; i < 4; ++i)
                #pragma unroll
                for (int j = 0; j < 2; ++j)
                    acc[i][j] = __builtin_amdgcn_mfma_f32_16x16x32_bf16(af[i], bfr[j], acc[i][j], 0, 0, 0);
        }
        __syncthreads();
    }

    // epilogue: C/D layout col=lane&15, row=(lane>>4)*4+reg; bf16 store
    #pragma unroll
    for (int j = 0; j < 2; ++j) {
        const int col = n0 + wn + j * 16 + l15;
        const float bv = bias[col];
        #pragma unroll
        for (int i = 0; i < 4; ++i) {
            const int rbase = m0 + wm + i * 16 + (lane >> 4) * 4;
            #pragma unroll
            for (int r = 0; r < 4; ++r)
                C[(size_t)(rbase + r) * DM + col] = f2bf(acc[i][j][r] + bv);
        }
    }

    if (vs) {
        const int b = m0 >> 11;   // tile never straddles batch boundary
        #pragma unroll
        for (int j = 0; j < 2; ++j) {
            float part = 0.f;
            #pragma unroll
            for (int i = 0; i < 4; ++i)
                #pragma unroll
                for (int r = 0; r < 4; ++r)
                    part += acc[i][j][r];
            part += __shfl_xor(part, 16, 64);
            part += __shfl_xor(part, 32, 64);
            if ((lane >> 4) == 0)
                atomicAdd(&vs[b * DM + n0 + wn + j * 16 + l15], part);
        }
    }
}

// ---------------- bf16 MFMA GEMM (all-bf16 staged via GLDS): output projection ----------------
template<int TGM, int TGN, int WMT, int WNT>
__device__ __forceinline__ void gemm_core(const unsigned short* __restrict__ A,
                                          const unsigned short* __restrict__ BT,
                                          const float* __restrict__ bias,
                                          float* __restrict__ C)
{
    __shared__ unsigned short S[(TGM + TGN) * GK];

    const int tid  = threadIdx.x;
    const int lane = tid & 63;
    const int wave = tid >> 6;
    constexpr int WAVES_M = TGM / (WMT * 16);
    const int wm = (wave % WAVES_M) * (WMT * 16);
    const int wn = (wave / WAVES_M) * (WNT * 16);
    const int m0 = blockIdx.y * TGM;
    const int n0 = blockIdx.x * TGN;
    const int l15 = lane & 15;
    const int q8  = (lane >> 4) * 8;

    f32x4 acc[WMT][WNT];
    #pragma unroll
    for (int i = 0; i < WMT; ++i)
        #pragma unroll
        for (int j = 0; j < WNT; ++j)
            acc[i][j] = (f32x4){0.f, 0.f, 0.f, 0.f};

    constexpr int NCH = (TGM + TGN) * 8;
    constexpr int NIT = NCH / 256;
    const unsigned short* gp[NIT];
    unsigned short* lp[NIT];
    #pragma unroll
    for (int it = 0; it < NIT; ++it) {
        const int c = tid + it * 256;
        if (c < TGM * 8) {
            const int kk = c / (TGM * 4);
            const int cr = c - kk * (TGM * 4);
            gp[it] = A + (size_t)(m0 + (cr >> 2)) * DM + kk * 32 + (cr & 3) * 8;
        } else {
            const int cb = c - TGM * 8;
            const int kk = cb / (TGN * 4);
            const int cr = cb - kk * (TGN * 4);
            gp[it] = BT + (size_t)(n0 + (cr >> 2)) * DM + kk * 32 + (cr & 3) * 8;
        }
        lp[it] = &S[(size_t)c * 8];
    }

    for (int k0 = 0; k0 < DM; k0 += GK) {
        #pragma unroll
        for (int it = 0; it < NIT; ++it)
            GLDS16(gp[it] + k0, lp[it]);
        __syncthreads();

        #pragma unroll
        for (int kk = 0; kk < 2; ++kk) {
            bf16x8 af[WMT], bfr[WNT];
            #pragma unroll
            for (int i = 0; i < WMT; ++i)
                af[i] = *(const bf16x8*)&S[kk * TGM * 32 + (wm + i * 16 + l15) * 32 + q8];
            #pragma unroll
            for (int j = 0; j < WNT; ++j)
                bfr[j] = *(const bf16x8*)&S[TGM * 64 + kk * TGN * 32 + (wn + j * 16 + l15) * 32 + q8];
            #pragma unroll
            for (int i = 0; i < WMT; ++i)
                #pragma unroll
                for (int j = 0; j < WNT; ++j)
                    acc[i][j] = __builtin_amdgcn_mfma_f32_16x16x32_bf16(af[i], bfr[j], acc[i][j], 0, 0, 0);
        }
        __syncthreads();
    }

    #pragma unroll
    for (int j = 0; j < WNT; ++j) {
        const int col = n0 + wn + j * 16 + l15;
        const float bv = bias[col];
        #pragma unroll
        for (int i = 0; i < WMT; ++i) {
            const int rbase = m0 + wm + i * 16 + (lane >> 4) * 4;
            #pragma unroll
            for (int r = 0; r < 4; ++r)
                C[(size_t)(rbase + r) * DM + col] = acc[i][j][r] + bv;
        }
    }
}

// out: 64x64 tile, grid (8, 64) = 512 blocks, f32 output
__global__ __launch_bounds__(256) void gemm_out(const unsigned short* A, const unsigned short* BT,
                                                const float* bias, float* C)
{
    gemm_core<64, 64, 2, 2>(A, BT, bias, C);
}

// ---------------- MFMA band attention, 4 waves/block ----------------
// Wave w of block x handles q-tile q0 = (x*4+w)*16 for (b,h) = blockIdx.y.
// QK^T: 2 n-tiles x 2 k-steps; w = exp(s*cnt/8)-1 on C-frag; den via 4-level shuffle;
// W -> A-frag via per-wave 1KB LDS region; PV: 4 n-tiles x 1 k-step.
// out_row = (vsum + sum w*v) / (SEQ + sum w)
__global__ __launch_bounds__(256) void attn_mfma(const unsigned short* __restrict__ Qb,
                                                 const unsigned short* __restrict__ Kb,
                                                 const unsigned short* __restrict__ Vb,
                                                 const float* __restrict__ vsum,
                                                 unsigned short* __restrict__ concat)
{
    __shared__ unsigned short Wlds[4][16 * 32];   // per-wave [q_local][kpos_local]
    const int tid  = threadIdx.x;
    const int lane = tid & 63;
    const int wave = tid >> 6;
    const int l15  = lane & 15;
    const int quad = lane >> 4;                // 0..3
    const int bh = blockIdx.y;
    const int b = bh >> 3, h = bh & 7;
    const int q0 = (blockIdx.x * 4 + wave) * 16;
    const size_t rowbase = (size_t)b * SEQ;
    const int dbase = h * DK;

    const unsigned short* qrow = Qb + (rowbase + q0 + l15) * DM + dbase + quad * 8;
    const bf16x8 aq0 = *(const bf16x8*)(qrow);
    const bf16x8 aq1 = *(const bf16x8*)(qrow + 32);

    f32x4 sc[2];
    #pragma unroll
    for (int t = 0; t < 2; ++t) {
        int kp = q0 - 4 + t * 16 + l15;
        kp = min(max(kp, 0), SEQ - 1);
        const unsigned short* krow = Kb + (rowbase + kp) * DM + dbase + quad * 8;
        const bf16x8 b0 = *(const bf16x8*)(krow);
        const bf16x8 b1 = *(const bf16x8*)(krow + 32);
        f32x4 z = (f32x4){0.f, 0.f, 0.f, 0.f};
        z = __builtin_amdgcn_mfma_f32_16x16x32_bf16(aq0, b0, z, 0, 0, 0);
        sc[t] = __builtin_amdgcn_mfma_f32_16x16x32_bf16(aq1, b1, z, 0, 0, 0);
    }

    float dsum[4] = {0.f, 0.f, 0.f, 0.f};
    #pragma unroll
    for (int t = 0; t < 2; ++t) {
        const int kpos = q0 - 4 + t * 16 + l15;   // unclamped
        #pragma unroll
        for (int r = 0; r < 4; ++r) {
            const int qq = q0 + quad * 4 + r;
            const int mn = min(qq, kpos), mx = qq + kpos - mn;
            const float cnt = (float)(min(mn + 2, SEQ - 1) - max(mx - 2, 0) + 1);
            const float cw = (kpos >= 0 && kpos < SEQ && (mx - mn) <= 4) ? cnt * 0.125f : 0.f;
            const float w = expf(sc[t][r] * cw) - 1.f;   // cw==0 -> exactly 0
            const unsigned short wb = f2bf(w);
            Wlds[wave][(quad * 4 + r) * 32 + t * 16 + l15] = wb;
            dsum[r] += bf2f(wb);
        }
    }
    #pragma unroll
    for (int off = 1; off <= 8; off <<= 1)
        #pragma unroll
        for (int r = 0; r < 4; ++r)
            dsum[r] += __shfl_xor(dsum[r], off, 64);

    __syncthreads();
    const bf16x8 aw = *(const bf16x8*)&Wlds[wave][l15 * 32 + quad * 8];

    #pragma unroll
    for (int nt = 0; nt < 4; ++nt) {
        const int d = dbase + nt * 16 + l15;
        bf16x8 bv_;
        #pragma unroll
        for (int j = 0; j < 8; ++j) {
            int kr = q0 - 4 + quad * 8 + j;
            kr = min(max(kr, 0), SEQ - 1);       // pad rows get w=0
            bv_[j] = (short)Vb[(rowbase + kr) * DM + d];
        }
        f32x4 z = (f32x4){0.f, 0.f, 0.f, 0.f};
        const f32x4 o = __builtin_amdgcn_mfma_f32_16x16x32_bf16(aw, bv_, z, 0, 0, 0);
        const float vs = vsum[b * DM + d];
        #pragma unroll
        for (int r = 0; r < 4; ++r) {
            const float den = (float)SEQ + dsum[r];
            concat[(rowbase + q0 + quad * 4 + r) * DM + d] = f2bf((vs + o[r]) / den);
        }
    }
}

extern "C" void kernel_launch(void* const* d_in, const int* in_sizes, int n_in,
                              void* d_out, int out_size, void* d_ws, size_t ws_size,
                              hipStream_t stream) {
    const float* q  = (const float*)d_in[0];
    const float* k  = (const float*)d_in[1];
    const float* v  = (const float*)d_in[2];
    const float* Wq = (const float*)d_in[3];
    const float* bq = (const float*)d_in[4];
    const float* Wk = (const float*)d_in[5];
    const float* bk = (const float*)d_in[6];
    const float* Wv = (const float*)d_in[7];
    const float* bv = (const float*)d_in[8];
    const float* Wo = (const float*)d_in[9];
    const float* bo = (const float*)d_in[10];

    const size_t NE = (size_t)MROWS * DM;  // 2,097,152

    float* vsum = (float*)d_ws;                        // 1024 floats
    unsigned short* Qb     = (unsigned short*)(vsum + 1024);
    unsigned short* Kb     = Qb + NE;
    unsigned short* Vb     = Kb + NE;
    unsigned short* WqT    = Vb + NE;
    unsigned short* WkT    = WqT + DM * DM;
    unsigned short* WvT    = WkT + DM * DM;
    unsigned short* WoT    = WvT + DM * DM;
    unsigned short* concat = WoT + DM * DM;

    // 1. weight transpose + vsum init (small)
    prep_w<<<1024, 256, 0, stream>>>(Wq, Wk, Wv, Wo, bv, WqT, WkT, WvT, WoT, vsum);

    // 2. Q/K/V projection GEMMs, fused f32->bf16 A-staging + fused V column-sum
    //    128x64 tiles, grid (8,32,3) = 768 blocks (3/CU balanced)
    gemm_qkv_cvt<<<dim3(DM / 64, MROWS / 128, 3), 256, 0, stream>>>(q, k, v, WqT, WkT, WvT,
                                                                    bq, bk, bv, Qb, Kb, Vb, vsum);

    // 3. MFMA band attention -> bf16 concat (512 blocks x 4 waves)
    attn_mfma<<<dim3(SEQ / 64, BS * NH), 256, 0, stream>>>(Qb, Kb, Vb, vsum, concat);

    // 4. output projection (512 blocks)
    gemm_out<<<dim3(DM / 64, MROWS / 64), 256, 0, stream>>>(concat, WoT, bo, (float*)d_out);
}

// Round 8
// 119.902 us; speedup vs baseline: 1.0983x; 1.0983x over previous
//
#include <hip/hip_runtime.h>
#include <hip/hip_bf16.h>

// bs=2, seq=2048, d_model=512, heads=8, d_k=64, WINDOW=2
#define SEQ 2048
#define DM  512
#define BS  2
#define NH  8
#define DK  64
#define MROWS (BS * SEQ)   // 4096
#define GK 64              // GEMM K-tile (two 16x16x32 MFMA k-steps per barrier pair)

typedef __attribute__((ext_vector_type(8))) short bf16x8;
typedef __attribute__((ext_vector_type(4))) float f32x4;

__device__ __forceinline__ unsigned short f2bf(float f) {
    unsigned int u = __float_as_uint(f);
    u += 0x7fff + ((u >> 16) & 1);
    return (unsigned short)(u >> 16);
}
__device__ __forceinline__ float bf2f(unsigned short b) {
    return __uint_as_float((unsigned int)b << 16);
}

// async global->LDS, 16B per lane. LDS dest must be wave-uniform base + lane*16.
#define GLDS16(g, l) __builtin_amdgcn_global_load_lds( \
    (const __attribute__((address_space(1))) void*)(g), \
    (__attribute__((address_space(3))) void*)(unsigned int)(unsigned long long)(l), 16, 0, 0)

// ---------------- prep (small): transpose+cvt weights; init vsum = SEQ*bv ----------------
__global__ __launch_bounds__(256) void prep_w(const float* __restrict__ Wq, const float* __restrict__ Wk,
                                              const float* __restrict__ Wv, const float* __restrict__ Wo,
                                              const float* __restrict__ bv_,
                                              unsigned short* __restrict__ WqT, unsigned short* __restrict__ WkT,
                                              unsigned short* __restrict__ WvT, unsigned short* __restrict__ WoT,
                                              float* __restrict__ vsum)
{
    __shared__ float tile[32][33];
    const int bid = blockIdx.x;            // 0..1023
    if (bid == 0) {
        #pragma unroll
        for (int t = 0; t < 4; ++t) {
            const int idx = threadIdx.x * 4 + t;           // 0..1023
            vsum[idx] = (float)SEQ * bv_[idx & (DM - 1)];
        }
    }
    const int z = bid >> 8;
    const int tl = bid & 255;
    const float* W = (z == 0) ? Wq : (z == 1) ? Wk : (z == 2) ? Wv : Wo;
    unsigned short* T = (z == 0) ? WqT : (z == 1) ? WkT : (z == 2) ? WvT : WoT;
    const int n0 = (tl & 15) * 32, k0 = (tl >> 4) * 32;
    const int tx = threadIdx.x & 31;
    const int ty = threadIdx.x >> 5;
    #pragma unroll
    for (int r = 0; r < 32; r += 8)
        tile[ty + r][tx] = W[(size_t)(k0 + ty + r) * DM + n0 + tx];
    __syncthreads();
    #pragma unroll
    for (int r = 0; r < 32; r += 8)
        T[(size_t)(n0 + ty + r) * DM + k0 + tx] = f2bf(tile[tx][ty + r]);
}

// ---------------- QKV projection GEMM with fused f32->bf16 A-staging ----------------
// C(bf16, 4096x512) = cvt_bf16(A f32) @ BT(bf16)^T + bias.  Tile 64x128, GK=64.
// Grid (4,64,3) = 768 blocks (3/CU balanced); A elements staged by 4 blocks (same
// total staging traffic as 128x128 tiling, but balanced block count).
// A staged via registers (load f32 -> RNE cvt -> ds_write); B via global_load_lds.
// z==2 (V) also accumulates raw per-column sums into vsum (bias pre-folded).
__global__ __launch_bounds__(256) void gemm_qkv_cvt(const float* __restrict__ q,
                                                    const float* __restrict__ k,
                                                    const float* __restrict__ v,
                                                    const unsigned short* __restrict__ WqT,
                                                    const unsigned short* __restrict__ WkT,
                                                    const unsigned short* __restrict__ WvT,
                                                    const float* __restrict__ bq, const float* __restrict__ bk,
                                                    const float* __restrict__ bvp,
                                                    unsigned short* __restrict__ Qb, unsigned short* __restrict__ Kb,
                                                    unsigned short* __restrict__ Vb, float* __restrict__ vsum)
{
    // A region: [kk][row64][32] = 4096 shorts (8 KB); B region at 4096: [kk][row128][32] = 8192 shorts (16 KB)
    __shared__ unsigned short S[12288];

    const float* Af; const unsigned short* BT; const float* bias; unsigned short* C; float* vs;
    if (blockIdx.z == 0)      { Af = q; BT = WqT; bias = bq; C = Qb; vs = nullptr; }
    else if (blockIdx.z == 1) { Af = k; BT = WkT; bias = bk; C = Kb; vs = nullptr; }
    else                      { Af = v; BT = WvT; bias = bvp; C = Vb; vs = vsum; }

    const int tid  = threadIdx.x;
    const int lane = tid & 63;
    const int wave = tid >> 6;
    const int wm = (wave & 1) * 32;       // wave tile 32x64
    const int wn = (wave >> 1) * 64;
    const int m0 = blockIdx.y * 64;
    const int n0 = blockIdx.x * 128;
    const int l15 = lane & 15;
    const int q8  = (lane >> 4) * 8;

    f32x4 acc[2][4];
    #pragma unroll
    for (int i = 0; i < 2; ++i)
        #pragma unroll
        for (int j = 0; j < 4; ++j)
            acc[i][j] = (f32x4){0.f, 0.f, 0.f, 0.f};

    // A-staging mapping: pass p in [0,4): row = p*16 + (tid>>4), cols (tid&15)*4 .. +3
    const int arow = tid >> 4;             // 0..15
    const int akl  = (tid & 15) * 4;       // 0..60
    const int awoff = ((akl >> 5) * 2048) + (akl & 31);   // + row*32 (shorts); kk stride 2048

    // B chunks: 1024 x 16B per K-tile, 4 per thread.  LDS B region [kk][n][32].
    const unsigned short* gb[4];
    unsigned short* lb[4];
    #pragma unroll
    for (int it = 0; it < 4; ++it) {
        const int c = tid + it * 256;
        const int n  = (c >> 2) & 127;
        const int kk = c >> 9;
        gb[it] = BT + (size_t)(n0 + n) * DM + kk * 32 + (c & 3) * 8;
        lb[it] = &S[4096 + c * 8];
    }

    for (int k0 = 0; k0 < DM; k0 += GK) {
        #pragma unroll
        for (int it = 0; it < 4; ++it)
            GLDS16(gb[it] + k0, lb[it]);

        float4 av[4];
        #pragma unroll
        for (int p = 0; p < 4; ++p)
            av[p] = *(const float4*)(Af + (size_t)(m0 + p * 16 + arow) * DM + k0 + akl);
        #pragma unroll
        for (int p = 0; p < 4; ++p) {
            ushort4 o;
            o.x = f2bf(av[p].x); o.y = f2bf(av[p].y); o.z = f2bf(av[p].z); o.w = f2bf(av[p].w);
            *(ushort4*)&S[awoff + (p * 16 + arow) * 32] = o;
        }
        __syncthreads();

        #pragma unroll
        for (int kk = 0; kk < 2; ++kk) {
            bf16x8 af[2], bfr[4];
            #pragma unroll
            for (int i = 0; i < 2; ++i)
                af[i] = *(const bf16x8*)&S[kk * 2048 + (wm + i * 16 + l15) * 32 + q8];
            #pragma unroll
            for (int j = 0; j < 4; ++j)
                bfr[j] = *(const bf16x8*)&S[4096 + kk * 4096 + (wn + j * 16 + l15) * 32 + q8];
            #pragma unroll
            for (int i = 0; i < 2; ++i)
                #pragma unroll
                for (int j = 0; j < 4; ++j)
                    acc[i][j] = __builtin_amdgcn_mfma_f32_16x16x32_bf16(af[i], bfr[j], acc[i][j], 0, 0, 0);
        }
        __syncthreads();
    }

    // epilogue: C/D layout col=lane&15, row=(lane>>4)*4+reg; bf16 store
    #pragma unroll
    for (int j = 0; j < 4; ++j) {
        const int col = n0 + wn + j * 16 + l15;
        const float bv = bias[col];
        #pragma unroll
        for (int i = 0; i < 2; ++i) {
            const int rbase = m0 + wm + i * 16 + (lane >> 4) * 4;
            #pragma unroll
            for (int r = 0; r < 4; ++r)
                C[(size_t)(rbase + r) * DM + col] = f2bf(acc[i][j][r] + bv);
        }
    }

    if (vs) {
        const int b = m0 >> 11;   // 64-row tiles never straddle the batch boundary
        #pragma unroll
        for (int j = 0; j < 4; ++j) {
            float part = 0.f;
            #pragma unroll
            for (int i = 0; i < 2; ++i)
                #pragma unroll
                for (int r = 0; r < 4; ++r)
                    part += acc[i][j][r];
            part += __shfl_xor(part, 16, 64);
            part += __shfl_xor(part, 32, 64);
            if ((lane >> 4) == 0)
                atomicAdd(&vs[b * DM + n0 + wn + j * 16 + l15], part);
        }
    }
}

// ---------------- bf16 MFMA GEMM (all-bf16 staged via GLDS): output projection ----------------
template<int TGM, int TGN, int WMT, int WNT>
__device__ __forceinline__ void gemm_core(const unsigned short* __restrict__ A,
                                          const unsigned short* __restrict__ BT,
                                          const float* __restrict__ bias,
                                          float* __restrict__ C)
{
    __shared__ unsigned short S[(TGM + TGN) * GK];

    const int tid  = threadIdx.x;
    const int lane = tid & 63;
    const int wave = tid >> 6;
    constexpr int WAVES_M = TGM / (WMT * 16);
    const int wm = (wave % WAVES_M) * (WMT * 16);
    const int wn = (wave / WAVES_M) * (WNT * 16);
    const int m0 = blockIdx.y * TGM;
    const int n0 = blockIdx.x * TGN;
    const int l15 = lane & 15;
    const int q8  = (lane >> 4) * 8;

    f32x4 acc[WMT][WNT];
    #pragma unroll
    for (int i = 0; i < WMT; ++i)
        #pragma unroll
        for (int j = 0; j < WNT; ++j)
            acc[i][j] = (f32x4){0.f, 0.f, 0.f, 0.f};

    constexpr int NCH = (TGM + TGN) * 8;
    constexpr int NIT = NCH / 256;
    const unsigned short* gp[NIT];
    unsigned short* lp[NIT];
    #pragma unroll
    for (int it = 0; it < NIT; ++it) {
        const int c = tid + it * 256;
        if (c < TGM * 8) {
            const int kk = c / (TGM * 4);
            const int cr = c - kk * (TGM * 4);
            gp[it] = A + (size_t)(m0 + (cr >> 2)) * DM + kk * 32 + (cr & 3) * 8;
        } else {
            const int cb = c - TGM * 8;
            const int kk = cb / (TGN * 4);
            const int cr = cb - kk * (TGN * 4);
            gp[it] = BT + (size_t)(n0 + (cr >> 2)) * DM + kk * 32 + (cr & 3) * 8;
        }
        lp[it] = &S[(size_t)c * 8];
    }

    for (int k0 = 0; k0 < DM; k0 += GK) {
        #pragma unroll
        for (int it = 0; it < NIT; ++it)
            GLDS16(gp[it] + k0, lp[it]);
        __syncthreads();

        #pragma unroll
        for (int kk = 0; kk < 2; ++kk) {
            bf16x8 af[WMT], bfr[WNT];
            #pragma unroll
            for (int i = 0; i < WMT; ++i)
                af[i] = *(const bf16x8*)&S[kk * TGM * 32 + (wm + i * 16 + l15) * 32 + q8];
            #pragma unroll
            for (int j = 0; j < WNT; ++j)
                bfr[j] = *(const bf16x8*)&S[TGM * 64 + kk * TGN * 32 + (wn + j * 16 + l15) * 32 + q8];
            #pragma unroll
            for (int i = 0; i < WMT; ++i)
                #pragma unroll
                for (int j = 0; j < WNT; ++j)
                    acc[i][j] = __builtin_amdgcn_mfma_f32_16x16x32_bf16(af[i], bfr[j], acc[i][j], 0, 0, 0);
        }
        __syncthreads();
    }

    #pragma unroll
    for (int j = 0; j < WNT; ++j) {
        const int col = n0 + wn + j * 16 + l15;
        const float bv = bias[col];
        #pragma unroll
        for (int i = 0; i < WMT; ++i) {
            const int rbase = m0 + wm + i * 16 + (lane >> 4) * 4;
            #pragma unroll
            for (int r = 0; r < 4; ++r)
                C[(size_t)(rbase + r) * DM + col] = acc[i][j][r] + bv;
        }
    }
}

// out: 64x64 tile, grid (8, 64) = 512 blocks, f32 output
__global__ __launch_bounds__(256) void gemm_out(const unsigned short* A, const unsigned short* BT,
                                                const float* bias, float* C)
{
    gemm_core<64, 64, 2, 2>(A, BT, bias, C);
}

// ---------------- MFMA band attention ----------------
// One wave per (b,h, 16-q tile). QK^T: 2 n-tiles x 2 k-steps of 16x16x32 bf16.
// w = exp(s*cnt/8)-1 on C-frag; den via 4-level shuffle; W -> A-frag via 1KB LDS;
// PV: 4 n-tiles x 1 k-step.  out_row = (vsum + sum w*v) / (SEQ + sum w)
__global__ __launch_bounds__(64) void attn_mfma(const unsigned short* __restrict__ Qb,
                                                const unsigned short* __restrict__ Kb,
                                                const unsigned short* __restrict__ Vb,
                                                const float* __restrict__ vsum,
                                                unsigned short* __restrict__ concat)
{
    __shared__ unsigned short Wlds[16 * 32];   // [q_local][kpos_local]
    const int lane = threadIdx.x;              // 0..63
    const int l15  = lane & 15;
    const int quad = lane >> 4;                // 0..3
    const int bh = blockIdx.y;
    const int b = bh >> 3, h = bh & 7;
    const int q0 = blockIdx.x * 16;
    const size_t rowbase = (size_t)b * SEQ;
    const int dbase = h * DK;

    const unsigned short* qrow = Qb + (rowbase + q0 + l15) * DM + dbase + quad * 8;
    const bf16x8 aq0 = *(const bf16x8*)(qrow);
    const bf16x8 aq1 = *(const bf16x8*)(qrow + 32);

    f32x4 sc[2];
    #pragma unroll
    for (int t = 0; t < 2; ++t) {
        int kp = q0 - 4 + t * 16 + l15;
        kp = min(max(kp, 0), SEQ - 1);
        const unsigned short* krow = Kb + (rowbase + kp) * DM + dbase + quad * 8;
        const bf16x8 b0 = *(const bf16x8*)(krow);
        const bf16x8 b1 = *(const bf16x8*)(krow + 32);
        f32x4 z = (f32x4){0.f, 0.f, 0.f, 0.f};
        z = __builtin_amdgcn_mfma_f32_16x16x32_bf16(aq0, b0, z, 0, 0, 0);
        sc[t] = __builtin_amdgcn_mfma_f32_16x16x32_bf16(aq1, b1, z, 0, 0, 0);
    }

    float dsum[4] = {0.f, 0.f, 0.f, 0.f};
    #pragma unroll
    for (int t = 0; t < 2; ++t) {
        const int kpos = q0 - 4 + t * 16 + l15;   // unclamped
        #pragma unroll
        for (int r = 0; r < 4; ++r) {
            const int qq = q0 + quad * 4 + r;
            const int mn = min(qq, kpos), mx = qq + kpos - mn;
            const float cnt = (float)(min(mn + 2, SEQ - 1) - max(mx - 2, 0) + 1);
            const float cw = (kpos >= 0 && kpos < SEQ && (mx - mn) <= 4) ? cnt * 0.125f : 0.f;
            const float w = expf(sc[t][r] * cw) - 1.f;   // cw==0 -> exactly 0
            const unsigned short wb = f2bf(w);
            Wlds[(quad * 4 + r) * 32 + t * 16 + l15] = wb;
            dsum[r] += bf2f(wb);
        }
    }
    #pragma unroll
    for (int off = 1; off <= 8; off <<= 1)
        #pragma unroll
        for (int r = 0; r < 4; ++r)
            dsum[r] += __shfl_xor(dsum[r], off, 64);

    __syncthreads();
    const bf16x8 aw = *(const bf16x8*)&Wlds[l15 * 32 + quad * 8];

    #pragma unroll
    for (int nt = 0; nt < 4; ++nt) {
        const int d = dbase + nt * 16 + l15;
        bf16x8 bv_;
        #pragma unroll
        for (int j = 0; j < 8; ++j) {
            int kr = q0 - 4 + quad * 8 + j;
            kr = min(max(kr, 0), SEQ - 1);       // pad rows get w=0
            bv_[j] = (short)Vb[(rowbase + kr) * DM + d];
        }
        f32x4 z = (f32x4){0.f, 0.f, 0.f, 0.f};
        const f32x4 o = __builtin_amdgcn_mfma_f32_16x16x32_bf16(aw, bv_, z, 0, 0, 0);
        const float vs = vsum[b * DM + d];
        #pragma unroll
        for (int r = 0; r < 4; ++r) {
            const float den = (float)SEQ + dsum[r];
            concat[(rowbase + q0 + quad * 4 + r) * DM + d] = f2bf((vs + o[r]) / den);
        }
    }
}

extern "C" void kernel_launch(void* const* d_in, const int* in_sizes, int n_in,
                              void* d_out, int out_size, void* d_ws, size_t ws_size,
                              hipStream_t stream) {
    const float* q  = (const float*)d_in[0];
    const float* k  = (const float*)d_in[1];
    const float* v  = (const float*)d_in[2];
    const float* Wq = (const float*)d_in[3];
    const float* bq = (const float*)d_in[4];
    const float* Wk = (const float*)d_in[5];
    const float* bk = (const float*)d_in[6];
    const float* Wv = (const float*)d_in[7];
    const float* bv = (const float*)d_in[8];
    const float* Wo = (const float*)d_in[9];
    const float* bo = (const float*)d_in[10];

    const size_t NE = (size_t)MROWS * DM;  // 2,097,152

    float* vsum = (float*)d_ws;                        // 1024 floats
    unsigned short* Qb     = (unsigned short*)(vsum + 1024);
    unsigned short* Kb     = Qb + NE;
    unsigned short* Vb     = Kb + NE;
    unsigned short* WqT    = Vb + NE;
    unsigned short* WkT    = WqT + DM * DM;
    unsigned short* WvT    = WkT + DM * DM;
    unsigned short* WoT    = WvT + DM * DM;
    unsigned short* concat = WoT + DM * DM;

    // 1. weight transpose + vsum init (small)
    prep_w<<<1024, 256, 0, stream>>>(Wq, Wk, Wv, Wo, bv, WqT, WkT, WvT, WoT, vsum);

    // 2. Q/K/V projection GEMMs, fused f32->bf16 A-staging + fused V column-sum
    //    64x128 tiles, grid (4,64,3) = 768 blocks (3/CU balanced)
    gemm_qkv_cvt<<<dim3(DM / 128, MROWS / 64, 3), 256, 0, stream>>>(q, k, v, WqT, WkT, WvT,
                                                                    bq, bk, bv, Qb, Kb, Vb, vsum);

    // 3. MFMA band attention -> bf16 concat (2048 waves, 8/CU)
    attn_mfma<<<dim3(SEQ / 16, BS * NH), 64, 0, stream>>>(Qb, Kb, Vb, vsum, concat);

    // 4. output projection (512 blocks)
    gemm_out<<<dim3(DM / 64, MROWS / 64), 256, 0, stream>>>(concat, WoT, bo, (float*)d_out);
}

// Round 9
// 118.306 us; speedup vs baseline: 1.1131x; 1.0135x over previous
//
#include <hip/hip_runtime.h>
#include <hip/hip_bf16.h>

// bs=2, seq=2048, d_model=512, heads=8, d_k=64, WINDOW=2
#define SEQ 2048
#define DM  512
#define BS  2
#define NH  8
#define DK  64
#define MROWS (BS * SEQ)   // 4096
#define GK 64              // GEMM K-tile (two 16x16x32 MFMA k-steps per barrier pair)

typedef __attribute__((ext_vector_type(8))) short bf16x8;
typedef __attribute__((ext_vector_type(4))) float f32x4;

__device__ __forceinline__ unsigned short f2bf(float f) {
    unsigned int u = __float_as_uint(f);
    u += 0x7fff + ((u >> 16) & 1);
    return (unsigned short)(u >> 16);
}
__device__ __forceinline__ float bf2f(unsigned short b) {
    return __uint_as_float((unsigned int)b << 16);
}

// async global->LDS, 16B per lane. LDS dest must be wave-uniform base + lane*16.
#define GLDS16(g, l) __builtin_amdgcn_global_load_lds( \
    (const __attribute__((address_space(1))) void*)(g), \
    (__attribute__((address_space(3))) void*)(unsigned int)(unsigned long long)(l), 16, 0, 0)

// ---------------- prep (small): transpose+cvt weights; init vsum = SEQ*bv ----------------
__global__ __launch_bounds__(256) void prep_w(const float* __restrict__ Wq, const float* __restrict__ Wk,
                                              const float* __restrict__ Wv, const float* __restrict__ Wo,
                                              const float* __restrict__ bv_,
                                              unsigned short* __restrict__ WqT, unsigned short* __restrict__ WkT,
                                              unsigned short* __restrict__ WvT, unsigned short* __restrict__ WoT,
                                              float* __restrict__ vsum)
{
    __shared__ float tile[32][33];
    const int bid = blockIdx.x;            // 0..1023
    if (bid == 0) {
        #pragma unroll
        for (int t = 0; t < 4; ++t) {
            const int idx = threadIdx.x * 4 + t;           // 0..1023
            vsum[idx] = (float)SEQ * bv_[idx & (DM - 1)];
        }
    }
    const int z = bid >> 8;
    const int tl = bid & 255;
    const float* W = (z == 0) ? Wq : (z == 1) ? Wk : (z == 2) ? Wv : Wo;
    unsigned short* T = (z == 0) ? WqT : (z == 1) ? WkT : (z == 2) ? WvT : WoT;
    const int n0 = (tl & 15) * 32, k0 = (tl >> 4) * 32;
    const int tx = threadIdx.x & 31;
    const int ty = threadIdx.x >> 5;
    #pragma unroll
    for (int r = 0; r < 32; r += 8)
        tile[ty + r][tx] = W[(size_t)(k0 + ty + r) * DM + n0 + tx];
    __syncthreads();
    #pragma unroll
    for (int r = 0; r < 32; r += 8)
        T[(size_t)(n0 + ty + r) * DM + k0 + tx] = f2bf(tile[tx][ty + r]);
}

// ---------------- QKV projection GEMM with fused f32->bf16 A-staging ----------------
// C(bf16, 4096x512) = cvt_bf16(A f32) @ BT(bf16)^T + bias.  Tile 64x128, GK=64.
// 1D grid 768, XCD-swizzled: all 4 n-blocks of one (z,m) strip share blockIdx%8
// (same XCD) so the 128KB f32 A-strip is L2-resident after the first reader.
// A staged via registers (load f32 -> RNE cvt -> ds_write); B via global_load_lds.
// z==2 (V) also accumulates raw per-column sums into vsum (bias pre-folded).
__global__ __launch_bounds__(256) void gemm_qkv_cvt(const float* __restrict__ q,
                                                    const float* __restrict__ k,
                                                    const float* __restrict__ v,
                                                    const unsigned short* __restrict__ WqT,
                                                    const unsigned short* __restrict__ WkT,
                                                    const unsigned short* __restrict__ WvT,
                                                    const float* __restrict__ bq, const float* __restrict__ bk,
                                                    const float* __restrict__ bvp,
                                                    unsigned short* __restrict__ Qb, unsigned short* __restrict__ Kb,
                                                    unsigned short* __restrict__ Vb, float* __restrict__ vsum)
{
    // A region: [kk][row64][32] = 4096 shorts (8 KB); B region at 4096: [kk][row128][32] (16 KB)
    __shared__ unsigned short S[12288];

    // XCD swizzle decode: g = xcd + 8*n + 32*t; strip = t*8+xcd; z = strip/64, m = strip%64
    const int g = blockIdx.x;                 // 0..767
    const int xcd   = g & 7;
    const int n_idx = (g >> 3) & 3;
    const int t     = g >> 5;                 // 0..23
    const int strip = t * 8 + xcd;            // 0..191
    const int z     = strip >> 6;             // 0..2
    const int m0    = (strip & 63) * 64;
    const int n0    = n_idx * 128;

    const float* Af; const unsigned short* BT; const float* bias; unsigned short* C; float* vs;
    if (z == 0)      { Af = q; BT = WqT; bias = bq; C = Qb; vs = nullptr; }
    else if (z == 1) { Af = k; BT = WkT; bias = bk; C = Kb; vs = nullptr; }
    else             { Af = v; BT = WvT; bias = bvp; C = Vb; vs = vsum; }

    const int tid  = threadIdx.x;
    const int lane = tid & 63;
    const int wave = tid >> 6;
    const int wm = (wave & 1) * 32;       // wave tile 32x64
    const int wn = (wave >> 1) * 64;
    const int l15 = lane & 15;
    const int q8  = (lane >> 4) * 8;

    f32x4 acc[2][4];
    #pragma unroll
    for (int i = 0; i < 2; ++i)
        #pragma unroll
        for (int j = 0; j < 4; ++j)
            acc[i][j] = (f32x4){0.f, 0.f, 0.f, 0.f};

    // A-staging mapping: pass p in [0,4): row = p*16 + (tid>>4), cols (tid&15)*4 .. +3
    const int arow = tid >> 4;             // 0..15
    const int akl  = (tid & 15) * 4;       // 0..60
    const int awoff = ((akl >> 5) * 2048) + (akl & 31);   // + row*32 (shorts); kk stride 2048

    // B chunks: 1024 x 16B per K-tile, 4 per thread.  LDS B region [kk][n][32].
    const unsigned short* gb[4];
    unsigned short* lb[4];
    #pragma unroll
    for (int it = 0; it < 4; ++it) {
        const int c = tid + it * 256;
        const int n  = (c >> 2) & 127;
        const int kk = c >> 9;
        gb[it] = BT + (size_t)(n0 + n) * DM + kk * 32 + (c & 3) * 8;
        lb[it] = &S[4096 + c * 8];
    }

    for (int k0 = 0; k0 < DM; k0 += GK) {
        #pragma unroll
        for (int it = 0; it < 4; ++it)
            GLDS16(gb[it] + k0, lb[it]);

        float4 av[4];
        #pragma unroll
        for (int p = 0; p < 4; ++p)
            av[p] = *(const float4*)(Af + (size_t)(m0 + p * 16 + arow) * DM + k0 + akl);
        #pragma unroll
        for (int p = 0; p < 4; ++p) {
            ushort4 o;
            o.x = f2bf(av[p].x); o.y = f2bf(av[p].y); o.z = f2bf(av[p].z); o.w = f2bf(av[p].w);
            *(ushort4*)&S[awoff + (p * 16 + arow) * 32] = o;
        }
        __syncthreads();

        #pragma unroll
        for (int kk = 0; kk < 2; ++kk) {
            bf16x8 af[2], bfr[4];
            #pragma unroll
            for (int i = 0; i < 2; ++i)
                af[i] = *(const bf16x8*)&S[kk * 2048 + (wm + i * 16 + l15) * 32 + q8];
            #pragma unroll
            for (int j = 0; j < 4; ++j)
                bfr[j] = *(const bf16x8*)&S[4096 + kk * 4096 + (wn + j * 16 + l15) * 32 + q8];
            #pragma unroll
            for (int i = 0; i < 2; ++i)
                #pragma unroll
                for (int j = 0; j < 4; ++j)
                    acc[i][j] = __builtin_amdgcn_mfma_f32_16x16x32_bf16(af[i], bfr[j], acc[i][j], 0, 0, 0);
        }
        __syncthreads();
    }

    // epilogue: C/D layout col=lane&15, row=(lane>>4)*4+reg; bf16 store
    #pragma unroll
    for (int j = 0; j < 4; ++j) {
        const int col = n0 + wn + j * 16 + l15;
        const float bv = bias[col];
        #pragma unroll
        for (int i = 0; i < 2; ++i) {
            const int rbase = m0 + wm + i * 16 + (lane >> 4) * 4;
            #pragma unroll
            for (int r = 0; r < 4; ++r)
                C[(size_t)(rbase + r) * DM + col] = f2bf(acc[i][j][r] + bv);
        }
    }

    if (vs) {
        const int b = m0 >> 11;   // 64-row tiles never straddle the batch boundary
        #pragma unroll
        for (int j = 0; j < 4; ++j) {
            float part = 0.f;
            #pragma unroll
            for (int i = 0; i < 2; ++i)
                #pragma unroll
                for (int r = 0; r < 4; ++r)
                    part += acc[i][j][r];
            part += __shfl_xor(part, 16, 64);
            part += __shfl_xor(part, 32, 64);
            if ((lane >> 4) == 0)
                atomicAdd(&vs[b * DM + n0 + wn + j * 16 + l15], part);
        }
    }
}

// ---------------- bf16 MFMA GEMM (all-bf16 staged via GLDS): output projection ----------------
// m0/n0 passed in (caller decodes an XCD-swizzled 1D grid).
template<int TGM, int TGN, int WMT, int WNT>
__device__ __forceinline__ void gemm_core(const unsigned short* __restrict__ A,
                                          const unsigned short* __restrict__ BT,
                                          const float* __restrict__ bias,
                                          float* __restrict__ C,
                                          const int m0, const int n0)
{
    __shared__ unsigned short S[(TGM + TGN) * GK];

    const int tid  = threadIdx.x;
    const int lane = tid & 63;
    const int wave = tid >> 6;
    constexpr int WAVES_M = TGM / (WMT * 16);
    const int wm = (wave % WAVES_M) * (WMT * 16);
    const int wn = (wave / WAVES_M) * (WNT * 16);
    const int l15 = lane & 15;
    const int q8  = (lane >> 4) * 8;

    f32x4 acc[WMT][WNT];
    #pragma unroll
    for (int i = 0; i < WMT; ++i)
        #pragma unroll
        for (int j = 0; j < WNT; ++j)
            acc[i][j] = (f32x4){0.f, 0.f, 0.f, 0.f};

    constexpr int NCH = (TGM + TGN) * 8;
    constexpr int NIT = NCH / 256;
    const unsigned short* gp[NIT];
    unsigned short* lp[NIT];
    #pragma unroll
    for (int it = 0; it < NIT; ++it) {
        const int c = tid + it * 256;
        if (c < TGM * 8) {
            const int kk = c / (TGM * 4);
            const int cr = c - kk * (TGM * 4);
            gp[it] = A + (size_t)(m0 + (cr >> 2)) * DM + kk * 32 + (cr & 3) * 8;
        } else {
            const int cb = c - TGM * 8;
            const int kk = cb / (TGN * 4);
            const int cr = cb - kk * (TGN * 4);
            gp[it] = BT + (size_t)(n0 + (cr >> 2)) * DM + kk * 32 + (cr & 3) * 8;
        }
        lp[it] = &S[(size_t)c * 8];
    }

    for (int k0 = 0; k0 < DM; k0 += GK) {
        #pragma unroll
        for (int it = 0; it < NIT; ++it)
            GLDS16(gp[it] + k0, lp[it]);
        __syncthreads();

        #pragma unroll
        for (int kk = 0; kk < 2; ++kk) {
            bf16x8 af[WMT], bfr[WNT];
            #pragma unroll
            for (int i = 0; i < WMT; ++i)
                af[i] = *(const bf16x8*)&S[kk * TGM * 32 + (wm + i * 16 + l15) * 32 + q8];
            #pragma unroll
            for (int j = 0; j < WNT; ++j)
                bfr[j] = *(const bf16x8*)&S[TGM * 64 + kk * TGN * 32 + (wn + j * 16 + l15) * 32 + q8];
            #pragma unroll
            for (int i = 0; i < WMT; ++i)
                #pragma unroll
                for (int j = 0; j < WNT; ++j)
                    acc[i][j] = __builtin_amdgcn_mfma_f32_16x16x32_bf16(af[i], bfr[j], acc[i][j], 0, 0, 0);
        }
        __syncthreads();
    }

    #pragma unroll
    for (int j = 0; j < WNT; ++j) {
        const int col = n0 + wn + j * 16 + l15;
        const float bv = bias[col];
        #pragma unroll
        for (int i = 0; i < WMT; ++i) {
            const int rbase = m0 + wm + i * 16 + (lane >> 4) * 4;
            #pragma unroll
            for (int r = 0; r < 4; ++r)
                C[(size_t)(rbase + r) * DM + col] = acc[i][j][r] + bv;
        }
    }
}

// out: 64x64 tile, 1D grid 512, XCD-swizzled: 8 n-blocks of one m-strip share blockIdx%8
__global__ __launch_bounds__(256) void gemm_out(const unsigned short* A, const unsigned short* BT,
                                                const float* bias, float* C)
{
    const int g = blockIdx.x;                // 0..511
    const int xcd   = g & 7;
    const int n_idx = (g >> 3) & 7;
    const int m_idx = (g >> 6) * 8 + xcd;    // 0..63
    gemm_core<64, 64, 2, 2>(A, BT, bias, C, m_idx * 64, n_idx * 64);
}

// ---------------- MFMA band attention ----------------
// One wave per (b,h, 16-q tile). QK^T: 2 n-tiles x 2 k-steps of 16x16x32 bf16.
// w = exp(s*cnt/8)-1 on C-frag; den via 4-level shuffle; W -> A-frag via 1KB LDS;
// PV: 4 n-tiles x 1 k-step.  out_row = (vsum + sum w*v) / (SEQ + sum w)
__global__ __launch_bounds__(64) void attn_mfma(const unsigned short* __restrict__ Qb,
                                                const unsigned short* __restrict__ Kb,
                                                const unsigned short* __restrict__ Vb,
                                                const float* __restrict__ vsum,
                                                unsigned short* __restrict__ concat)
{
    __shared__ unsigned short Wlds[16 * 32];   // [q_local][kpos_local]
    const int lane = threadIdx.x;              // 0..63
    const int l15  = lane & 15;
    const int quad = lane >> 4;                // 0..3
    const int bh = blockIdx.y;
    const int b = bh >> 3, h = bh & 7;
    const int q0 = blockIdx.x * 16;
    const size_t rowbase = (size_t)b * SEQ;
    const int dbase = h * DK;

    const unsigned short* qrow = Qb + (rowbase + q0 + l15) * DM + dbase + quad * 8;
    const bf16x8 aq0 = *(const bf16x8*)(qrow);
    const bf16x8 aq1 = *(const bf16x8*)(qrow + 32);

    f32x4 sc[2];
    #pragma unroll
    for (int t = 0; t < 2; ++t) {
        int kp = q0 - 4 + t * 16 + l15;
        kp = min(max(kp, 0), SEQ - 1);
        const unsigned short* krow = Kb + (rowbase + kp) * DM + dbase + quad * 8;
        const bf16x8 b0 = *(const bf16x8*)(krow);
        const bf16x8 b1 = *(const bf16x8*)(krow + 32);
        f32x4 z = (f32x4){0.f, 0.f, 0.f, 0.f};
        z = __builtin_amdgcn_mfma_f32_16x16x32_bf16(aq0, b0, z, 0, 0, 0);
        sc[t] = __builtin_amdgcn_mfma_f32_16x16x32_bf16(aq1, b1, z, 0, 0, 0);
    }

    float dsum[4] = {0.f, 0.f, 0.f, 0.f};
    #pragma unroll
    for (int t = 0; t < 2; ++t) {
        const int kpos = q0 - 4 + t * 16 + l15;   // unclamped
        #pragma unroll
        for (int r = 0; r < 4; ++r) {
            const int qq = q0 + quad * 4 + r;
            const int mn = min(qq, kpos), mx = qq + kpos - mn;
            const float cnt = (float)(min(mn + 2, SEQ - 1) - max(mx - 2, 0) + 1);
            const float cw = (kpos >= 0 && kpos < SEQ && (mx - mn) <= 4) ? cnt * 0.125f : 0.f;
            const float w = expf(sc[t][r] * cw) - 1.f;   // cw==0 -> exactly 0
            const unsigned short wb = f2bf(w);
            Wlds[(quad * 4 + r) * 32 + t * 16 + l15] = wb;
            dsum[r] += bf2f(wb);
        }
    }
    #pragma unroll
    for (int off = 1; off <= 8; off <<= 1)
        #pragma unroll
        for (int r = 0; r < 4; ++r)
            dsum[r] += __shfl_xor(dsum[r], off, 64);

    __syncthreads();
    const bf16x8 aw = *(const bf16x8*)&Wlds[l15 * 32 + quad * 8];

    #pragma unroll
    for (int nt = 0; nt < 4; ++nt) {
        const int d = dbase + nt * 16 + l15;
        bf16x8 bv_;
        #pragma unroll
        for (int j = 0; j < 8; ++j) {
            int kr = q0 - 4 + quad * 8 + j;
            kr = min(max(kr, 0), SEQ - 1);       // pad rows get w=0
            bv_[j] = (short)Vb[(rowbase + kr) * DM + d];
        }
        f32x4 z = (f32x4){0.f, 0.f, 0.f, 0.f};
        const f32x4 o = __builtin_amdgcn_mfma_f32_16x16x32_bf16(aw, bv_, z, 0, 0, 0);
        const float vs = vsum[b * DM + d];
        #pragma unroll
        for (int r = 0; r < 4; ++r) {
            const float den = (float)SEQ + dsum[r];
            concat[(rowbase + q0 + quad * 4 + r) * DM + d] = f2bf((vs + o[r]) / den);
        }
    }
}

extern "C" void kernel_launch(void* const* d_in, const int* in_sizes, int n_in,
                              void* d_out, int out_size, void* d_ws, size_t ws_size,
                              hipStream_t stream) {
    const float* q  = (const float*)d_in[0];
    const float* k  = (const float*)d_in[1];
    const float* v  = (const float*)d_in[2];
    const float* Wq = (const float*)d_in[3];
    const float* bq = (const float*)d_in[4];
    const float* Wk = (const float*)d_in[5];
    const float* bk = (const float*)d_in[6];
    const float* Wv = (const float*)d_in[7];
    const float* bv = (const float*)d_in[8];
    const float* Wo = (const float*)d_in[9];
    const float* bo = (const float*)d_in[10];

    const size_t NE = (size_t)MROWS * DM;  // 2,097,152

    float* vsum = (float*)d_ws;                        // 1024 floats
    unsigned short* Qb     = (unsigned short*)(vsum + 1024);
    unsigned short* Kb     = Qb + NE;
    unsigned short* Vb     = Kb + NE;
    unsigned short* WqT    = Vb + NE;
    unsigned short* WkT    = WqT + DM * DM;
    unsigned short* WvT    = WkT + DM * DM;
    unsigned short* WoT    = WvT + DM * DM;
    unsigned short* concat = WoT + DM * DM;

    // 1. weight transpose + vsum init (small)
    prep_w<<<1024, 256, 0, stream>>>(Wq, Wk, Wv, Wo, bv, WqT, WkT, WvT, WoT, vsum);

    // 2. Q/K/V projection GEMMs, fused f32->bf16 A-staging + fused V column-sum
    //    64x128 tiles, 1D grid 768 XCD-swizzled (3/CU balanced, A-strips L2-local)
    gemm_qkv_cvt<<<768, 256, 0, stream>>>(q, k, v, WqT, WkT, WvT,
                                          bq, bk, bv, Qb, Kb, Vb, vsum);

    // 3. MFMA band attention -> bf16 concat (2048 waves, 8/CU)
    attn_mfma<<<dim3(SEQ / 16, BS * NH), 64, 0, stream>>>(Qb, Kb, Vb, vsum, concat);

    // 4. output projection (1D grid 512, XCD-swizzled)
    gemm_out<<<512, 256, 0, stream>>>(concat, WoT, bo, (float*)d_out);
}